// Round 17
// baseline (143.328 us; speedup 1.0000x reference)
//
#include <hip/hip_runtime.h>
#include <hip/hip_bf16.h>
#include <math.h>

#define B_ 2
#define N_ 2048
#define D_ 512
#define E_ 1024
#define S_ 16
#define R_ 32
#define C_ 512
#define FC_ 128    // fine chunks of 16 tokens (p1/hend/comb/p3)
#define FCH_ 16

using short8 = __attribute__((ext_vector_type(8))) short;
using f32x4  = __attribute__((ext_vector_type(4))) float;
using f32x16 = __attribute__((ext_vector_type(16))) float;

#define LOG2E 1.44269504f

__device__ __forceinline__ short f2bf(float f) {
    union { float f; unsigned u; } x; x.f = f;
    unsigned r = (x.u + 0x7fffu + ((x.u >> 16) & 1u)) >> 16;
    return (short)r;
}
__device__ __forceinline__ float bf2f(short s) {
    union { unsigned u; float f; } x;
    x.u = ((unsigned)(unsigned short)s) << 16;
    return x.f;
}
// wave-level async global->LDS, 16B per lane (lds dest wave-uniform base + lane*16)
__device__ __forceinline__ void gl_lds16(const void* g, void* l) {
    __builtin_amdgcn_global_load_lds((const __attribute__((address_space(1))) void*)g,
                                     (__attribute__((address_space(3))) void*)l, 16, 0, 0);
}

__device__ __forceinline__ void transpose32(const float* __restrict__ W, short* __restrict__ Wt,
                                            int K, int N, int bx, int by, float (*t)[33], int tid) {
    int n0 = bx * 32, k0 = by * 32;
    int c = tid & 31, rr0 = tid >> 5;
#pragma unroll
    for (int rr = rr0; rr < 32; rr += 8)
        t[rr][c] = W[(size_t)(k0 + rr) * N + n0 + c];
    __syncthreads();
#pragma unroll
    for (int rr = rr0; rr < 32; rr += 8)
        Wt[(size_t)(n0 + rr) * K + k0 + c] = f2bf(t[c][rr]);
}

// ================= K1: LN stats+apply (wave/token) | W_in^T =================
__global__ __launch_bounds__(256) void prep1_kernel(
    const float* __restrict__ x, short* __restrict__ xnb,
    const float* __restrict__ lng, const float* __restrict__ lnb,
    const float* __restrict__ W_in, short* __restrict__ Wint) {
    __shared__ __align__(16) float smem[32 * 33];
    int bid = blockIdx.x;
    int tid = threadIdx.x;
    if (bid < 1024) {
        int t = bid * 4 + (tid >> 6);
        int lane = tid & 63;
        const float* src = x + (size_t)t * D_ + lane * 8;
        float4 v0 = *(const float4*)src;
        float4 v1 = *(const float4*)(src + 4);
        float s = v0.x + v0.y + v0.z + v0.w + v1.x + v1.y + v1.z + v1.w;
        float s2 = v0.x * v0.x;
        s2 = fmaf(v0.y, v0.y, s2); s2 = fmaf(v0.z, v0.z, s2); s2 = fmaf(v0.w, v0.w, s2);
        s2 = fmaf(v1.x, v1.x, s2); s2 = fmaf(v1.y, v1.y, s2);
        s2 = fmaf(v1.z, v1.z, s2); s2 = fmaf(v1.w, v1.w, s2);
#pragma unroll
        for (int o = 32; o >= 1; o >>= 1) {
            s += __shfl_xor(s, o);
            s2 += __shfl_xor(s2, o);
        }
        float mu = s * (1.f / (float)D_);
        float var = s2 * (1.f / (float)D_) - mu * mu;
        float rs = rsqrtf(var + 1e-5f);
        float4 g0 = *(const float4*)(lng + lane * 8);
        float4 g1 = *(const float4*)(lng + lane * 8 + 4);
        float4 b0 = *(const float4*)(lnb + lane * 8);
        float4 b1 = *(const float4*)(lnb + lane * 8 + 4);
        short8 o;
        o[0] = f2bf((v0.x - mu) * rs * g0.x + b0.x);
        o[1] = f2bf((v0.y - mu) * rs * g0.y + b0.y);
        o[2] = f2bf((v0.z - mu) * rs * g0.z + b0.z);
        o[3] = f2bf((v0.w - mu) * rs * g0.w + b0.w);
        o[4] = f2bf((v1.x - mu) * rs * g1.x + b1.x);
        o[5] = f2bf((v1.y - mu) * rs * g1.y + b1.y);
        o[6] = f2bf((v1.z - mu) * rs * g1.z + b1.z);
        o[7] = f2bf((v1.w - mu) * rs * g1.w + b1.w);
        *(short8*)(xnb + (size_t)t * D_ + lane * 8) = o;
    } else {
        int r = bid - 1024;
        transpose32(W_in, Wint, 512, 2048, r % 64, r / 64, (float(*)[33])smem, tid);
    }
}

// ================= K2 hybrid: gemm1 tiles | film | W_out^T | W_x^T | W_dt^T =================
__global__ __launch_bounds__(256) void gemm1_hybrid(
    const short* __restrict__ A, const short* __restrict__ Bt, short* __restrict__ Cb,
    const float* __restrict__ W_out, short* __restrict__ Woutt,
    const float* __restrict__ W_x, short* __restrict__ Wxt,
    const float* __restrict__ W_dt, short* __restrict__ Wdtt,
    const float* __restrict__ cond,
    const float* __restrict__ gw, const float* __restrict__ gb,
    const float* __restrict__ bw, const float* __restrict__ bb,
    float* __restrict__ gamma, float* __restrict__ beta) {
    __shared__ __align__(16) char smem[32768];
    int bid = blockIdx.x;
    int tid = threadIdx.x;
    if (bid < 512) {
        constexpr int BM = 128, BN = 128, BK = 64;
        constexpr int N = 2048, K = 512;
        short* As = (short*)smem;
        short* Bs = As + BM * BK;
        int lane = tid & 63, w = tid >> 6;
        int wr = w >> 1, wc = w & 1;
        int swz = (bid & 7) * 64 + (bid >> 3);
        int m0 = (swz >> 4) * BM, n0 = (swz & 15) * BN;
        int lr = lane >> 3, lc = lane & 7;
        f32x16 acc[2][2];
#pragma unroll
        for (int i = 0; i < 2; i++)
#pragma unroll
            for (int j = 0; j < 2; j++)
#pragma unroll
                for (int r = 0; r < 16; r++) acc[i][j][r] = 0.f;
        int l31 = lane & 31, hk = (lane >> 5) * 8;
        for (int k0 = 0; k0 < K; k0 += BK) {
            __syncthreads();
#pragma unroll
            for (int ch = w; ch < BM / 8; ch += 4)
                gl_lds16(&A[(size_t)(m0 + ch * 8 + lr) * K + k0 + lc * 8], &As[ch * 512]);
#pragma unroll
            for (int ch = w; ch < BN / 8; ch += 4)
                gl_lds16(&Bt[(size_t)(n0 + ch * 8 + lr) * K + k0 + lc * 8], &Bs[ch * 512]);
            __syncthreads();
#pragma unroll
            for (int kk = 0; kk < 4; kk++) {
                short8 a[2], b[2];
#pragma unroll
                for (int i = 0; i < 2; i++)
                    a[i] = *(const short8*)&As[(wr * 64 + i * 32 + l31) * BK + kk * 16 + hk];
#pragma unroll
                for (int j = 0; j < 2; j++)
                    b[j] = *(const short8*)&Bs[(wc * 64 + j * 32 + l31) * BK + kk * 16 + hk];
#pragma unroll
                for (int i = 0; i < 2; i++)
#pragma unroll
                    for (int j = 0; j < 2; j++)
                        acc[i][j] = __builtin_amdgcn_mfma_f32_32x32x16_bf16(a[i], b[j], acc[i][j], 0, 0, 0);
            }
        }
        int rbase = 4 * (lane >> 5);
#pragma unroll
        for (int i = 0; i < 2; i++)
#pragma unroll
            for (int j = 0; j < 2; j++) {
                int col = n0 + wc * 64 + j * 32 + l31;
#pragma unroll
                for (int r = 0; r < 16; r++) {
                    int row = m0 + wr * 64 + i * 32 + rbase + (r & 3) + 8 * (r >> 2);
                    Cb[(size_t)row * N + col] = f2bf(acc[i][j][r]);
                }
            }
    } else if (bid < 520) {
        float* cs = (float*)smem;           // [2][512]
        float* red = (float*)smem + 1024;   // [4][64][4]
        int d0 = (bid - 512) * 64;
#pragma unroll
        for (int i = tid; i < 2 * C_ / 4; i += 256) {
            int b = i >> 7;
            int c4 = (i & 127) * 4;
            *(float4*)&cs[b * C_ + c4] = *(const float4*)(cond + (size_t)b * C_ + c4);
        }
        __syncthreads();
        int dl = tid & 63, ks = tid >> 6;
        int d = d0 + dl;
        float g0 = 0.f, g1 = 0.f, bt0 = 0.f, bt1 = 0.f;
#pragma unroll 4
        for (int k = ks * 128; k < ks * 128 + 128; k++) {
            float wg = gw[(size_t)k * D_ + d];
            float wb = bw[(size_t)k * D_ + d];
            float c0 = cs[k], c1 = cs[C_ + k];
            g0 = fmaf(c0, wg, g0);
            g1 = fmaf(c1, wg, g1);
            bt0 = fmaf(c0, wb, bt0);
            bt1 = fmaf(c1, wb, bt1);
        }
        red[(ks * 64 + dl) * 4 + 0] = g0; red[(ks * 64 + dl) * 4 + 1] = g1;
        red[(ks * 64 + dl) * 4 + 2] = bt0; red[(ks * 64 + dl) * 4 + 3] = bt1;
        __syncthreads();
        if (ks == 0) {
            float s0 = 0.f, s1 = 0.f, s2 = 0.f, s3 = 0.f;
#pragma unroll
            for (int q = 0; q < 4; q++) {
                s0 += red[(q * 64 + dl) * 4 + 0]; s1 += red[(q * 64 + dl) * 4 + 1];
                s2 += red[(q * 64 + dl) * 4 + 2]; s3 += red[(q * 64 + dl) * 4 + 3];
            }
            float gbv = gb[d], bbv = bb[d];
            gamma[d] = s0 + gbv;
            gamma[D_ + d] = s1 + gbv;
            beta[d] = s2 + bbv;
            beta[D_ + d] = s3 + bbv;
        }
    } else if (bid < 1032) {
        int r = bid - 520;
        transpose32(W_out, Woutt, 1024, 512, r % 16, r / 16, (float(*)[33])smem, tid);
    } else if (bid < 1096) {
        int r = bid - 1032;
        transpose32(W_x, Wxt, 1024, 64, r % 2, r / 2, (float(*)[33])smem, tid);
    } else {
        int r = bid - 1096;
        transpose32(W_dt, Wdtt, 32, 1024, r, 0, (float(*)[33])smem, tid);
    }
}

// ---------------- gemm2: C[M][N] = A[M][K] * Bt[N][K]^T, FiLM, fp32 out ----------------
template <int BM, int BN>
__global__ __launch_bounds__(256) void gemm2_kernel(
    const short* __restrict__ A, const short* __restrict__ Bt, float* __restrict__ Cf,
    int M, int N, int K,
    const float* __restrict__ gamma, const float* __restrict__ beta) {
    constexpr int BK = 64;
    constexpr int WM = BM / 2, WN = BN / 2;
    constexpr int MR = WM / 32, NR = WN / 32;
    __shared__ __align__(16) short As[BM * BK];
    __shared__ __align__(16) short Bs[BN * BK];
    int tid = threadIdx.x;
    int lane = tid & 63, w = tid >> 6;
    int wr = w >> 1, wc = w & 1;
    int lid = blockIdx.x;
    int chunk = gridDim.x >> 3;
    int swz = (lid & 7) * chunk + (lid >> 3);
    int ntiles = N / BN;
    int m0 = (swz / ntiles) * BM, n0 = (swz % ntiles) * BN;
    int lr = lane >> 3, lc = lane & 7;

    f32x16 acc[MR][NR];
#pragma unroll
    for (int i = 0; i < MR; i++)
#pragma unroll
        for (int j = 0; j < NR; j++)
#pragma unroll
            for (int r = 0; r < 16; r++) acc[i][j][r] = 0.f;

    int l31 = lane & 31, hk = (lane >> 5) * 8;

    for (int k0 = 0; k0 < K; k0 += BK) {
        __syncthreads();
#pragma unroll
        for (int ch = w; ch < BM / 8; ch += 4)
            gl_lds16(&A[(size_t)(m0 + ch * 8 + lr) * K + k0 + lc * 8], &As[ch * 512]);
#pragma unroll
        for (int ch = w; ch < BN / 8; ch += 4)
            gl_lds16(&Bt[(size_t)(n0 + ch * 8 + lr) * K + k0 + lc * 8], &Bs[ch * 512]);
        __syncthreads();
#pragma unroll
        for (int kk = 0; kk < 4; kk++) {
            short8 a[MR], b[NR];
#pragma unroll
            for (int i = 0; i < MR; i++)
                a[i] = *(const short8*)&As[(wr * WM + i * 32 + l31) * BK + kk * 16 + hk];
#pragma unroll
            for (int j = 0; j < NR; j++)
                b[j] = *(const short8*)&Bs[(wc * WN + j * 32 + l31) * BK + kk * 16 + hk];
#pragma unroll
            for (int i = 0; i < MR; i++)
#pragma unroll
                for (int j = 0; j < NR; j++)
                    acc[i][j] = __builtin_amdgcn_mfma_f32_32x32x16_bf16(a[i], b[j], acc[i][j], 0, 0, 0);
        }
    }
    int rbase = 4 * (lane >> 5);
    int bi = m0 >> 11;
#pragma unroll
    for (int i = 0; i < MR; i++)
#pragma unroll
        for (int j = 0; j < NR; j++) {
            int col = n0 + wc * WN + j * 32 + l31;
            float gm = gamma[bi * D_ + col];
            float bt = beta[bi * D_ + col];
#pragma unroll
            for (int r = 0; r < 16; r++) {
                int row = m0 + wr * WM + i * 32 + rbase + (r & 3) + 8 * (r >> 2);
                Cf[(size_t)row * N + col] = gm * acc[i][j][r] + bt;
            }
        }
}

// ================= mid: sliding-window conv -> xproj -> dt; 16 tok/block, 8 waves =================
__global__ __launch_bounds__(512) void mid_kernel(
    const short* __restrict__ xzb, const float* __restrict__ cw, const float* __restrict__ cb,
    const short* __restrict__ Wxt,   // [64][1024] bf16
    const short* __restrict__ Wdtt,  // [1024][32] bf16
    const float* __restrict__ bdt,
    short* __restrict__ ucb, float* __restrict__ xdbl, short* __restrict__ deltab) {
    constexpr int LDU = 1032;                        // 2064B pitch
    __shared__ __align__(16) short u[16 * LDU];      // 33 KB uc (bf16)
    __shared__ __align__(16) float xd2[2][16 * 68];  // 8.7 KB x_dbl partials
    int tid = threadIdx.x;
    int t0 = blockIdx.x * 16;
    int n0 = t0 & (N_ - 1);
    // ---- conv+SiLU: thread -> 8-wide e-chunk, 4 tokens; 7-row sliding window ----
    {
        int c8 = (tid & 127) * 8;
        int base = (tid >> 7) * 4;
        float4 wv[8];
        float cbv[8];
#pragma unroll
        for (int j = 0; j < 8; j++) {
            wv[j] = *(const float4*)(cw + (c8 + j) * 4);
            cbv[j] = cb[c8 + j];
        }
        float uf[7][8];
#pragma unroll
        for (int j = 0; j < 7; j++) {
            short8 v = {0, 0, 0, 0, 0, 0, 0, 0};
            if (n0 + base - 3 + j >= 0)
                v = *(const short8*)&xzb[(size_t)(t0 + base - 3 + j) * (2 * E_) + c8];
#pragma unroll
            for (int q = 0; q < 8; q++) uf[j][q] = bf2f(v[q]);
        }
#pragma unroll
        for (int k = 0; k < 4; k++) {
            int n = base + k;
            short8 o;
#pragma unroll
            for (int q = 0; q < 8; q++) {
                float a = fmaf(wv[q].x, uf[k][q],
                          fmaf(wv[q].y, uf[k + 1][q],
                          fmaf(wv[q].z, uf[k + 2][q],
                          fmaf(wv[q].w, uf[k + 3][q], cbv[q]))));
                float v = a / (1.f + __expf(-a));
                o[q] = f2bf(v);
            }
            *(short8*)&ucb[(size_t)(t0 + n) * E_ + c8] = o;
            *(short8*)&u[n * LDU + c8] = o;
        }
    }
    __syncthreads();
    // ---- xproj: 8 waves; wave w -> cols [cg*16,+16), K-half kh ----
    int lane = tid & 63, w = tid >> 6;
    int cg = w & 3, kh = w >> 2;
    int l15 = lane & 15, kq = (lane >> 4) * 8;
    f32x4 acc4 = {0.f, 0.f, 0.f, 0.f};
#pragma unroll 8
    for (int k0 = 0; k0 < 16; k0++) {
        int kk = kh * 512 + k0 * 32;
        short8 af = *(const short8*)&u[l15 * LDU + kk + kq];
        short8 bfr = *(const short8*)&Wxt[(size_t)(cg * 16 + l15) * E_ + kk + kq];
        acc4 = __builtin_amdgcn_mfma_f32_16x16x32_bf16(af, bfr, acc4, 0, 0, 0);
    }
#pragma unroll
    for (int j = 0; j < 4; j++)
        xd2[kh][((lane >> 4) * 4 + j) * 68 + cg * 16 + l15] = acc4[j];
    __syncthreads();
    if (tid < 256) {
        int r = tid >> 4, c4 = (tid & 15) * 4;
        float4 a = *(const float4*)&xd2[0][r * 68 + c4];
        float4 b = *(const float4*)&xd2[1][r * 68 + c4];
        a.x += b.x; a.y += b.y; a.z += b.z; a.w += b.w;
        *(float4*)&xd2[0][r * 68 + c4] = a;
        *(float4*)&xdbl[(size_t)(t0 + r) * 64 + c4] = a;
    }
    __syncthreads();
    // ---- dt: 8 waves x 8 e-tiles of 16 ----
    float av[8];
    *(float4*)&av[0] = *(const float4*)&xd2[0][l15 * 68 + kq];
    *(float4*)&av[4] = *(const float4*)&xd2[0][l15 * 68 + kq + 4];
    short8 ab;
#pragma unroll
    for (int j = 0; j < 8; j++) ab[j] = f2bf(av[j]);
    int row4 = (lane >> 4) * 4;
#pragma unroll 4
    for (int t = 0; t < 8; t++) {
        int e = w * 128 + t * 16 + l15;
        short8 bb = *(const short8*)&Wdtt[(size_t)e * 32 + kq];
        f32x4 c4v = {0.f, 0.f, 0.f, 0.f};
        c4v = __builtin_amdgcn_mfma_f32_16x16x32_bf16(ab, bb, c4v, 0, 0, 0);
        float bv = bdt[e];
#pragma unroll
        for (int j = 0; j < 4; j++) {
            float xv = c4v[j] + bv;
            float sp = (xv > 20.f) ? xv : log1pf(__expf(xv));
            deltab[(size_t)(t0 + row4 + j) * E_ + e] = f2bf(sp);
        }
    }
}

// ---------------- scan p1: fine chunks of 16 tokens, 1024 blocks ----------------
__global__ __launch_bounds__(256) void scan_p1(const short* __restrict__ deltab,
                                               const short* __restrict__ ucb,
                                               const float* __restrict__ xdbl,
                                               const float* __restrict__ A_log,
                                               short* __restrict__ hend,
                                               float* __restrict__ cumd) {
    int blk = blockIdx.x;            // b*(FC*4) + c*4 + eq
    int eq = blk & 3;
    int c = (blk >> 2) & (FC_ - 1);
    int b = blk >> 9;
    int tid = threadIdx.x;
    int e = eq * 256 + tid;
    __shared__ float Bsl[FCH_][16];
    int base = (b * N_ + c * FCH_) * 64;
    if (tid < FCH_ * 16) {
        int n = tid >> 4, col = tid & 15;
        Bsl[n][col] = xdbl[base + n * 64 + R_ + col];
    }
    float Aes[16];
    const float4* al = (const float4*)(A_log + e * 16);
#pragma unroll
    for (int j = 0; j < 4; j++) {
        float4 a = al[j];
        Aes[j * 4 + 0] = -LOG2E * __expf(a.x);
        Aes[j * 4 + 1] = -LOG2E * __expf(a.y);
        Aes[j * 4 + 2] = -LOG2E * __expf(a.z);
        Aes[j * 4 + 3] = -LOG2E * __expf(a.w);
    }
    __syncthreads();
    float h[16];
#pragma unroll
    for (int s = 0; s < 16; s++) h[s] = 0.f;
    float cum = 0.f;
    const short* dp = deltab + (size_t)(b * N_ + c * FCH_) * E_ + e;
    const short* up = ucb + (size_t)(b * N_ + c * FCH_) * E_ + e;
#pragma unroll 2
    for (int n = 0; n < FCH_; n++) {
        float dv = bf2f(dp[n * E_]);
        float uv = bf2f(up[n * E_]);
        float du = dv * uv;
        cum += dv;
        float Bl[16];
#pragma unroll
        for (int j = 0; j < 4; j++) *(float4*)&Bl[j * 4] = *(const float4*)&Bsl[n][j * 4];
#pragma unroll
        for (int s = 0; s < 16; s++) {
            float dA = exp2f(dv * Aes[s]);
            h[s] = fmaf(dA, h[s], du * Bl[s]);
        }
    }
    size_t ob = (size_t)((b * FC_ + c) * 16) * E_ + e;
#pragma unroll
    for (int s = 0; s < 16; s++) hend[ob + (size_t)s * E_] = f2bf(h[s]);
    cumd[(size_t)(b * FC_ + c) * E_ + e] = cum;
}

// ---- comb: 128-chunk chains, pair-per-lane + 64-lane Kogge-Stone ----
__global__ __launch_bounds__(256) void scan_comb(short* __restrict__ hend,
                                                 const float* __restrict__ cumd,
                                                 const float* __restrict__ A_log) {
    __shared__ float lh[FC_][33];
    __shared__ float lp[FC_][33];
    int blk = blockIdx.x;          // b*512 + s*32 + et
    int et = blk & 31;
    int s = (blk >> 5) & 15;
    int b = blk >> 9;
    int e0 = et * 32;
    int tid = threadIdx.x;
    int lane = tid & 63, w = tid >> 6;
    for (int i = tid; i < FC_ * 32; i += 256) {
        int c = i >> 5, e = i & 31;
        lh[c][e] = bf2f(hend[((size_t)((b * FC_ + c) * 16) + s) * E_ + e0 + e]);
        lp[c][e] = cumd[(size_t)(b * FC_ + c) * E_ + e0 + e];
    }
    __syncthreads();
#pragma unroll
    for (int q = 0; q < 8; q++) {
        int e = w * 8 + q;
        float Aes = -LOG2E * __expf(A_log[(e0 + e) * 16 + s]);
        int c0 = 2 * lane, c1 = c0 + 1;
        float A0 = exp2f(Aes * lp[c0][e]);
        float B0 = lh[c0][e];
        float A1 = exp2f(Aes * lp[c1][e]);
        float B1 = lh[c1][e];
        float A = A1 * A0;
        float Bv = fmaf(A1, B0, B1);
#pragma unroll
        for (int off = 1; off < 64; off <<= 1) {
            float Ap = __shfl_up(A, off);
            float Bp = __shfl_up(Bv, off);
            if (lane >= off) {
                Bv = fmaf(A, Bp, Bv);
                A *= Ap;
            }
        }
        float pB = __shfl_up(Bv, 1);
        if (lane == 0) pB = 0.f;
        lh[c0][e] = pB;
        lh[c1][e] = fmaf(A0, pB, B0);
    }
    __syncthreads();
    for (int i = tid; i < FC_ * 32; i += 256) {
        int c = i >> 5, e = i & 31;
        hend[((size_t)((b * FC_ + c) * 16) + s) * E_ + e0 + e] = f2bf(lh[c][e]);
    }
}

// ---- p3: fine chunks of 16 tokens, 1024 blocks; gated y ----
__global__ __launch_bounds__(256) void scan_p3(const short* __restrict__ deltab,
                                               const short* __restrict__ ucb,
                                               const float* __restrict__ xdbl,
                                               const short* __restrict__ xzb,
                                               const float* __restrict__ A_log,
                                               const float* __restrict__ D_skip,
                                               const short* __restrict__ hend,
                                               short* __restrict__ yb) {
    int blk = blockIdx.x;
    int eq = blk & 3;
    int c = (blk >> 2) & (FC_ - 1);
    int b = blk >> 9;
    int tid = threadIdx.x;
    int e = eq * 256 + tid;
    __shared__ float Bsl[FCH_][16];
    __shared__ float Csl[FCH_][16];
    int base = (b * N_ + c * FCH_) * 64;
    if (tid < FCH_ * 32) {
        int n = tid >> 5, col = tid & 31;
        float v = xdbl[base + n * 64 + R_ + col];
        if (col < 16) Bsl[n][col] = v;
        else Csl[n][col - 16] = v;
    }
    float Aes[16];
    const float4* al = (const float4*)(A_log + e * 16);
#pragma unroll
    for (int j = 0; j < 4; j++) {
        float4 a = al[j];
        Aes[j * 4 + 0] = -LOG2E * __expf(a.x);
        Aes[j * 4 + 1] = -LOG2E * __expf(a.y);
        Aes[j * 4 + 2] = -LOG2E * __expf(a.z);
        Aes[j * 4 + 3] = -LOG2E * __expf(a.w);
    }
    float dsk = D_skip[e];
    float h[16];
    size_t ob = (size_t)((b * FC_ + c) * 16) * E_ + e;
#pragma unroll
    for (int s = 0; s < 16; s++) h[s] = bf2f(hend[ob + (size_t)s * E_]);
    __syncthreads();
    const short* dp = deltab + (size_t)(b * N_ + c * FCH_) * E_ + e;
    const short* up = ucb + (size_t)(b * N_ + c * FCH_) * E_ + e;
    const short* zp = xzb + (size_t)(b * N_ + c * FCH_) * (2 * E_) + E_ + e;
    short* yp = yb + (size_t)(b * N_ + c * FCH_) * E_ + e;
#pragma unroll 2
    for (int n = 0; n < FCH_; n++) {
        float dv = bf2f(dp[n * E_]);
        float uv = bf2f(up[n * E_]);
        float du = dv * uv;
        float Bl[16], Cl[16];
#pragma unroll
        for (int j = 0; j < 4; j++) {
            *(float4*)&Bl[j * 4] = *(const float4*)&Bsl[n][j * 4];
            *(float4*)&Cl[j * 4] = *(const float4*)&Csl[n][j * 4];
        }
        float y = 0.f;
#pragma unroll
        for (int s = 0; s < 16; s++) {
            float dA = exp2f(dv * Aes[s]);
            h[s] = fmaf(dA, h[s], du * Bl[s]);
            y = fmaf(h[s], Cl[s], y);
        }
        float zv = bf2f(zp[n * 2 * E_]);
        float yy = y + dsk * uv;
        yy = yy * (zv / (1.f + __expf(-zv)));
        yp[n * E_] = f2bf(yy);
    }
}

extern "C" void kernel_launch(void* const* d_in, const int* in_sizes, int n_in,
                              void* d_out, int out_size, void* d_ws, size_t ws_size,
                              hipStream_t stream) {
    const float* x       = (const float*)d_in[0];
    const float* cond    = (const float*)d_in[1];
    const float* ln_g    = (const float*)d_in[2];
    const float* ln_b    = (const float*)d_in[3];
    const float* W_in    = (const float*)d_in[4];
    const float* conv_w  = (const float*)d_in[5];
    const float* conv_b  = (const float*)d_in[6];
    const float* W_x     = (const float*)d_in[7];
    const float* W_dt    = (const float*)d_in[8];
    const float* b_dt    = (const float*)d_in[9];
    const float* A_log   = (const float*)d_in[10];
    const float* D_skip  = (const float*)d_in[11];
    const float* W_out   = (const float*)d_in[12];
    const float* film_gw = (const float*)d_in[13];
    const float* film_gb = (const float*)d_in[14];
    const float* film_bw = (const float*)d_in[15];
    const float* film_bb = (const float*)d_in[16];
    float* out = (float*)d_out;

    float* ws = (float*)d_ws;
    float* xdbl  = ws;                       //   262,144 f
    float* gamma = xdbl + 262144;            //     1,024 f
    float* beta  = gamma + 1024;             //     1,024 f
    float* cumd  = beta + 1024;              //   262,144 f  (B*FC*E)
    short* hend  = (short*)(cumd + 262144);  // 4,194,304 sh (bf16, B*FC*S*E)
    short* xzb   = hend + 4194304;           // 8,388,608 sh
    short* ucb   = xzb + 8388608;            // 4,194,304 sh
    short* deltab = ucb + 4194304;           // 4,194,304 sh
    short* Wint  = deltab + 4194304;         // 1,048,576 sh
    short* Woutt = Wint + 1048576;           //   524,288 sh
    short* yb    = Woutt + 524288;           // 4,194,304 sh
    short* Wxt   = yb + 4194304;             //    65,536 sh
    short* Wdtt  = Wxt + 65536;              //    32,768 sh
    short* xnb   = Wdtt + 32768;             // 2,097,152 sh

    // K1: LN stats+apply + W_in^T (2048 blocks)
    prep1_kernel<<<2048, 256, 0, stream>>>(x, xnb, ln_g, ln_b, W_in, Wint);

    // K2: gemm1 (512 XCD-swizzled tiles) + film + W_out^T + W_x^T + W_dt^T
    gemm1_hybrid<<<1128, 256, 0, stream>>>(
        xnb, Wint, xzb, W_out, Woutt, W_x, Wxt, W_dt, Wdtt,
        cond, film_gw, film_gb, film_bw, film_bb, gamma, beta);

    // K3: conv+silu -> xproj -> dt; 256 blocks x 8 waves
    mid_kernel<<<B_ * N_ / 16, 512, 0, stream>>>(
        xzb, conv_w, conv_b, Wxt, Wdtt, b_dt, ucb, xdbl, deltab);

    // K4: scan phase-1, fine chunks (1024 blocks)
    scan_p1<<<B_ * FC_ * 4, 256, 0, stream>>>(deltab, ucb, xdbl, A_log, hend, cumd);

    // K5: combine over 128 fine chunks (1024 blocks)
    scan_comb<<<B_ * S_ * 32, 256, 0, stream>>>(hend, cumd, A_log);

    // K6: phase-3 gated y, fine chunks (1024 blocks)
    scan_p3<<<B_ * FC_ * 4, 256, 0, stream>>>(deltab, ucb, xdbl, xzb, A_log, D_skip, hend, yb);

    // K7: out = FiLM(y @ W_out), 64x64 tiles, XCD-swizzled
    gemm2_kernel<64, 64>
        <<<512, 256, 0, stream>>>(
            yb, Woutt, out, B_ * N_, D_, E_, gamma, beta);
}

// Round 18
// 128.444 us; speedup vs baseline: 1.1159x; 1.1159x over previous
//
#include <hip/hip_runtime.h>
#include <hip/hip_bf16.h>
#include <math.h>

#define B_ 2
#define N_ 2048
#define D_ 512
#define E_ 1024
#define S_ 16
#define R_ 32
#define C_ 512
#define CH_ 32
#define NC_ 64     // chunks of 32 tokens

using short8 = __attribute__((ext_vector_type(8))) short;
using f32x4  = __attribute__((ext_vector_type(4))) float;
using f32x16 = __attribute__((ext_vector_type(16))) float;

__device__ __forceinline__ short f2bf(float f) {
    union { float f; unsigned u; } x; x.f = f;
    unsigned r = (x.u + 0x7fffu + ((x.u >> 16) & 1u)) >> 16;
    return (short)r;
}
__device__ __forceinline__ float bf2f(short s) {
    union { unsigned u; float f; } x;
    x.u = ((unsigned)(unsigned short)s) << 16;
    return x.f;
}
// wave-level async global->LDS, 16B per lane (lds dest wave-uniform base + lane*16)
__device__ __forceinline__ void gl_lds16(const void* g, void* l) {
    __builtin_amdgcn_global_load_lds((const __attribute__((address_space(1))) void*)g,
                                     (__attribute__((address_space(3))) void*)l, 16, 0, 0);
}

__device__ __forceinline__ void transpose32(const float* __restrict__ W, short* __restrict__ Wt,
                                            int K, int N, int bx, int by, float (*t)[33], int tid) {
    int n0 = bx * 32, k0 = by * 32;
    int c = tid & 31, rr0 = tid >> 5;
#pragma unroll
    for (int rr = rr0; rr < 32; rr += 8)
        t[rr][c] = W[(size_t)(k0 + rr) * N + n0 + c];
    __syncthreads();
#pragma unroll
    for (int rr = rr0; rr < 32; rr += 8)
        Wt[(size_t)(n0 + rr) * K + k0 + c] = f2bf(t[c][rr]);
}

// ================= K1: LN stats+apply (wave/token) | W_in^T =================
__global__ __launch_bounds__(256) void prep1_kernel(
    const float* __restrict__ x, short* __restrict__ xnb,
    const float* __restrict__ lng, const float* __restrict__ lnb,
    const float* __restrict__ W_in, short* __restrict__ Wint) {
    __shared__ __align__(16) float smem[32 * 33];
    int bid = blockIdx.x;
    int tid = threadIdx.x;
    if (bid < 1024) {
        int t = bid * 4 + (tid >> 6);
        int lane = tid & 63;
        const float* src = x + (size_t)t * D_ + lane * 8;
        float4 v0 = *(const float4*)src;
        float4 v1 = *(const float4*)(src + 4);
        float s = v0.x + v0.y + v0.z + v0.w + v1.x + v1.y + v1.z + v1.w;
        float s2 = v0.x * v0.x;
        s2 = fmaf(v0.y, v0.y, s2); s2 = fmaf(v0.z, v0.z, s2); s2 = fmaf(v0.w, v0.w, s2);
        s2 = fmaf(v1.x, v1.x, s2); s2 = fmaf(v1.y, v1.y, s2);
        s2 = fmaf(v1.z, v1.z, s2); s2 = fmaf(v1.w, v1.w, s2);
#pragma unroll
        for (int o = 32; o >= 1; o >>= 1) {
            s += __shfl_xor(s, o);
            s2 += __shfl_xor(s2, o);
        }
        float mu = s * (1.f / (float)D_);
        float var = s2 * (1.f / (float)D_) - mu * mu;
        float rs = rsqrtf(var + 1e-5f);
        float4 g0 = *(const float4*)(lng + lane * 8);
        float4 g1 = *(const float4*)(lng + lane * 8 + 4);
        float4 b0 = *(const float4*)(lnb + lane * 8);
        float4 b1 = *(const float4*)(lnb + lane * 8 + 4);
        short8 o;
        o[0] = f2bf((v0.x - mu) * rs * g0.x + b0.x);
        o[1] = f2bf((v0.y - mu) * rs * g0.y + b0.y);
        o[2] = f2bf((v0.z - mu) * rs * g0.z + b0.z);
        o[3] = f2bf((v0.w - mu) * rs * g0.w + b0.w);
        o[4] = f2bf((v1.x - mu) * rs * g1.x + b1.x);
        o[5] = f2bf((v1.y - mu) * rs * g1.y + b1.y);
        o[6] = f2bf((v1.z - mu) * rs * g1.z + b1.z);
        o[7] = f2bf((v1.w - mu) * rs * g1.w + b1.w);
        *(short8*)(xnb + (size_t)t * D_ + lane * 8) = o;
    } else {
        int r = bid - 1024;
        transpose32(W_in, Wint, 512, 2048, r % 64, r / 64, (float(*)[33])smem, tid);
    }
}

// ================= K2 hybrid: gemm1 tiles | film | W_out^T | W_x^T | W_dt^T =================
__global__ __launch_bounds__(256) void gemm1_hybrid(
    const short* __restrict__ A, const short* __restrict__ Bt, short* __restrict__ Cb,
    const float* __restrict__ W_out, short* __restrict__ Woutt,
    const float* __restrict__ W_x, short* __restrict__ Wxt,
    const float* __restrict__ W_dt, short* __restrict__ Wdtt,
    const float* __restrict__ cond,
    const float* __restrict__ gw, const float* __restrict__ gb,
    const float* __restrict__ bw, const float* __restrict__ bb,
    float* __restrict__ gamma, float* __restrict__ beta) {
    __shared__ __align__(16) char smem[32768];
    int bid = blockIdx.x;
    int tid = threadIdx.x;
    if (bid < 512) {
        constexpr int BM = 128, BN = 128, BK = 64;
        constexpr int N = 2048, K = 512;
        short* As = (short*)smem;
        short* Bs = As + BM * BK;
        int lane = tid & 63, w = tid >> 6;
        int wr = w >> 1, wc = w & 1;
        int swz = (bid & 7) * 64 + (bid >> 3);
        int m0 = (swz >> 4) * BM, n0 = (swz & 15) * BN;
        int lr = lane >> 3, lc = lane & 7;
        f32x16 acc[2][2];
#pragma unroll
        for (int i = 0; i < 2; i++)
#pragma unroll
            for (int j = 0; j < 2; j++)
#pragma unroll
                for (int r = 0; r < 16; r++) acc[i][j][r] = 0.f;
        int l31 = lane & 31, hk = (lane >> 5) * 8;
        for (int k0 = 0; k0 < K; k0 += BK) {
            __syncthreads();
#pragma unroll
            for (int ch = w; ch < BM / 8; ch += 4)
                gl_lds16(&A[(size_t)(m0 + ch * 8 + lr) * K + k0 + lc * 8], &As[ch * 512]);
#pragma unroll
            for (int ch = w; ch < BN / 8; ch += 4)
                gl_lds16(&Bt[(size_t)(n0 + ch * 8 + lr) * K + k0 + lc * 8], &Bs[ch * 512]);
            __syncthreads();
#pragma unroll
            for (int kk = 0; kk < 4; kk++) {
                short8 a[2], b[2];
#pragma unroll
                for (int i = 0; i < 2; i++)
                    a[i] = *(const short8*)&As[(wr * 64 + i * 32 + l31) * BK + kk * 16 + hk];
#pragma unroll
                for (int j = 0; j < 2; j++)
                    b[j] = *(const short8*)&Bs[(wc * 64 + j * 32 + l31) * BK + kk * 16 + hk];
#pragma unroll
                for (int i = 0; i < 2; i++)
#pragma unroll
                    for (int j = 0; j < 2; j++)
                        acc[i][j] = __builtin_amdgcn_mfma_f32_32x32x16_bf16(a[i], b[j], acc[i][j], 0, 0, 0);
            }
        }
        int rbase = 4 * (lane >> 5);
#pragma unroll
        for (int i = 0; i < 2; i++)
#pragma unroll
            for (int j = 0; j < 2; j++) {
                int col = n0 + wc * 64 + j * 32 + l31;
#pragma unroll
                for (int r = 0; r < 16; r++) {
                    int row = m0 + wr * 64 + i * 32 + rbase + (r & 3) + 8 * (r >> 2);
                    Cb[(size_t)row * N + col] = f2bf(acc[i][j][r]);
                }
            }
    } else if (bid < 520) {
        float* cs = (float*)smem;           // [2][512]
        float* red = (float*)smem + 1024;   // [4][64][4]
        int d0 = (bid - 512) * 64;
#pragma unroll
        for (int i = tid; i < 2 * C_ / 4; i += 256) {
            int b = i >> 7;
            int c4 = (i & 127) * 4;
            *(float4*)&cs[b * C_ + c4] = *(const float4*)(cond + (size_t)b * C_ + c4);
        }
        __syncthreads();
        int dl = tid & 63, ks = tid >> 6;
        int d = d0 + dl;
        float g0 = 0.f, g1 = 0.f, bt0 = 0.f, bt1 = 0.f;
#pragma unroll 4
        for (int k = ks * 128; k < ks * 128 + 128; k++) {
            float wg = gw[(size_t)k * D_ + d];
            float wb = bw[(size_t)k * D_ + d];
            float c0 = cs[k], c1 = cs[C_ + k];
            g0 = fmaf(c0, wg, g0);
            g1 = fmaf(c1, wg, g1);
            bt0 = fmaf(c0, wb, bt0);
            bt1 = fmaf(c1, wb, bt1);
        }
        red[(ks * 64 + dl) * 4 + 0] = g0; red[(ks * 64 + dl) * 4 + 1] = g1;
        red[(ks * 64 + dl) * 4 + 2] = bt0; red[(ks * 64 + dl) * 4 + 3] = bt1;
        __syncthreads();
        if (ks == 0) {
            float s0 = 0.f, s1 = 0.f, s2 = 0.f, s3 = 0.f;
#pragma unroll
            for (int q = 0; q < 4; q++) {
                s0 += red[(q * 64 + dl) * 4 + 0]; s1 += red[(q * 64 + dl) * 4 + 1];
                s2 += red[(q * 64 + dl) * 4 + 2]; s3 += red[(q * 64 + dl) * 4 + 3];
            }
            float gbv = gb[d], bbv = bb[d];
            gamma[d] = s0 + gbv;
            gamma[D_ + d] = s1 + gbv;
            beta[d] = s2 + bbv;
            beta[D_ + d] = s3 + bbv;
        }
    } else if (bid < 1032) {
        int r = bid - 520;
        transpose32(W_out, Woutt, 1024, 512, r % 16, r / 16, (float(*)[33])smem, tid);
    } else if (bid < 1096) {
        int r = bid - 1032;
        transpose32(W_x, Wxt, 1024, 64, r % 2, r / 2, (float(*)[33])smem, tid);
    } else {
        int r = bid - 1096;
        transpose32(W_dt, Wdtt, 32, 1024, r, 0, (float(*)[33])smem, tid);
    }
}

// ---------------- gemm2: C[M][N] = A[M][K] * Bt[N][K]^T, FiLM, fp32 out ----------------
template <int BM, int BN>
__global__ __launch_bounds__(256) void gemm2_kernel(
    const short* __restrict__ A, const short* __restrict__ Bt, float* __restrict__ Cf,
    int M, int N, int K,
    const float* __restrict__ gamma, const float* __restrict__ beta) {
    constexpr int BK = 64;
    constexpr int WM = BM / 2, WN = BN / 2;
    constexpr int MR = WM / 32, NR = WN / 32;
    __shared__ __align__(16) short As[BM * BK];
    __shared__ __align__(16) short Bs[BN * BK];
    int tid = threadIdx.x;
    int lane = tid & 63, w = tid >> 6;
    int wr = w >> 1, wc = w & 1;
    int lid = blockIdx.x;
    int chunk = gridDim.x >> 3;
    int swz = (lid & 7) * chunk + (lid >> 3);
    int ntiles = N / BN;
    int m0 = (swz / ntiles) * BM, n0 = (swz % ntiles) * BN;
    int lr = lane >> 3, lc = lane & 7;

    f32x16 acc[MR][NR];
#pragma unroll
    for (int i = 0; i < MR; i++)
#pragma unroll
        for (int j = 0; j < NR; j++)
#pragma unroll
            for (int r = 0; r < 16; r++) acc[i][j][r] = 0.f;

    int l31 = lane & 31, hk = (lane >> 5) * 8;

    for (int k0 = 0; k0 < K; k0 += BK) {
        __syncthreads();
#pragma unroll
        for (int ch = w; ch < BM / 8; ch += 4)
            gl_lds16(&A[(size_t)(m0 + ch * 8 + lr) * K + k0 + lc * 8], &As[ch * 512]);
#pragma unroll
        for (int ch = w; ch < BN / 8; ch += 4)
            gl_lds16(&Bt[(size_t)(n0 + ch * 8 + lr) * K + k0 + lc * 8], &Bs[ch * 512]);
        __syncthreads();
#pragma unroll
        for (int kk = 0; kk < 4; kk++) {
            short8 a[MR], b[NR];
#pragma unroll
            for (int i = 0; i < MR; i++)
                a[i] = *(const short8*)&As[(wr * WM + i * 32 + l31) * BK + kk * 16 + hk];
#pragma unroll
            for (int j = 0; j < NR; j++)
                b[j] = *(const short8*)&Bs[(wc * WN + j * 32 + l31) * BK + kk * 16 + hk];
#pragma unroll
            for (int i = 0; i < MR; i++)
#pragma unroll
                for (int j = 0; j < NR; j++)
                    acc[i][j] = __builtin_amdgcn_mfma_f32_32x32x16_bf16(a[i], b[j], acc[i][j], 0, 0, 0);
        }
    }
    int rbase = 4 * (lane >> 5);
    int bi = m0 >> 11;
#pragma unroll
    for (int i = 0; i < MR; i++)
#pragma unroll
        for (int j = 0; j < NR; j++) {
            int col = n0 + wc * WN + j * 32 + l31;
            float gm = gamma[bi * D_ + col];
            float bt = beta[bi * D_ + col];
#pragma unroll
            for (int r = 0; r < 16; r++) {
                int row = m0 + wr * WM + i * 32 + rbase + (r & 3) + 8 * (r >> 2);
                Cf[(size_t)row * N + col] = gm * acc[i][j][r] + bt;
            }
        }
}

// ================= mid: sliding-window conv -> xproj -> dt; 16 tok/block, 8 waves =================
__global__ __launch_bounds__(512) void mid_kernel(
    const short* __restrict__ xzb, const float* __restrict__ cw, const float* __restrict__ cb,
    const short* __restrict__ Wxt,   // [64][1024] bf16
    const short* __restrict__ Wdtt,  // [1024][32] bf16
    const float* __restrict__ bdt,
    short* __restrict__ ucb, float* __restrict__ xdbl, short* __restrict__ deltab) {
    constexpr int LDU = 1032;                        // 2064B pitch
    __shared__ __align__(16) short u[16 * LDU];      // 33 KB uc (bf16)
    __shared__ __align__(16) float xd2[2][16 * 68];  // 8.7 KB x_dbl partials
    int tid = threadIdx.x;
    int t0 = blockIdx.x * 16;
    int n0 = t0 & (N_ - 1);
    // ---- conv+SiLU: thread -> 8-wide e-chunk, 4 tokens; 7-row sliding window ----
    {
        int c8 = (tid & 127) * 8;
        int base = (tid >> 7) * 4;
        float4 wv[8];
        float cbv[8];
#pragma unroll
        for (int j = 0; j < 8; j++) {
            wv[j] = *(const float4*)(cw + (c8 + j) * 4);
            cbv[j] = cb[c8 + j];
        }
        float uf[7][8];
#pragma unroll
        for (int j = 0; j < 7; j++) {
            short8 v = {0, 0, 0, 0, 0, 0, 0, 0};
            if (n0 + base - 3 + j >= 0)
                v = *(const short8*)&xzb[(size_t)(t0 + base - 3 + j) * (2 * E_) + c8];
#pragma unroll
            for (int q = 0; q < 8; q++) uf[j][q] = bf2f(v[q]);
        }
#pragma unroll
        for (int k = 0; k < 4; k++) {
            int n = base + k;
            short8 o;
#pragma unroll
            for (int q = 0; q < 8; q++) {
                float a = fmaf(wv[q].x, uf[k][q],
                          fmaf(wv[q].y, uf[k + 1][q],
                          fmaf(wv[q].z, uf[k + 2][q],
                          fmaf(wv[q].w, uf[k + 3][q], cbv[q]))));
                float v = a / (1.f + __expf(-a));
                o[q] = f2bf(v);
            }
            *(short8*)&ucb[(size_t)(t0 + n) * E_ + c8] = o;
            *(short8*)&u[n * LDU + c8] = o;
        }
    }
    __syncthreads();
    // ---- xproj: 8 waves; wave w -> cols [cg*16,+16), K-half kh ----
    int lane = tid & 63, w = tid >> 6;
    int cg = w & 3, kh = w >> 2;
    int l15 = lane & 15, kq = (lane >> 4) * 8;
    f32x4 acc4 = {0.f, 0.f, 0.f, 0.f};
#pragma unroll 8
    for (int k0 = 0; k0 < 16; k0++) {
        int kk = kh * 512 + k0 * 32;
        short8 af = *(const short8*)&u[l15 * LDU + kk + kq];
        short8 bfr = *(const short8*)&Wxt[(size_t)(cg * 16 + l15) * E_ + kk + kq];
        acc4 = __builtin_amdgcn_mfma_f32_16x16x32_bf16(af, bfr, acc4, 0, 0, 0);
    }
#pragma unroll
    for (int j = 0; j < 4; j++)
        xd2[kh][((lane >> 4) * 4 + j) * 68 + cg * 16 + l15] = acc4[j];
    __syncthreads();
    if (tid < 256) {
        int r = tid >> 4, c4 = (tid & 15) * 4;
        float4 a = *(const float4*)&xd2[0][r * 68 + c4];
        float4 b = *(const float4*)&xd2[1][r * 68 + c4];
        a.x += b.x; a.y += b.y; a.z += b.z; a.w += b.w;
        *(float4*)&xd2[0][r * 68 + c4] = a;
        *(float4*)&xdbl[(size_t)(t0 + r) * 64 + c4] = a;
    }
    __syncthreads();
    // ---- dt: 8 waves x 8 e-tiles of 16 ----
    float av[8];
    *(float4*)&av[0] = *(const float4*)&xd2[0][l15 * 68 + kq];
    *(float4*)&av[4] = *(const float4*)&xd2[0][l15 * 68 + kq + 4];
    short8 ab;
#pragma unroll
    for (int j = 0; j < 8; j++) ab[j] = f2bf(av[j]);
    int row4 = (lane >> 4) * 4;
#pragma unroll 4
    for (int t = 0; t < 8; t++) {
        int e = w * 128 + t * 16 + l15;
        short8 bb = *(const short8*)&Wdtt[(size_t)e * 32 + kq];
        f32x4 c4v = {0.f, 0.f, 0.f, 0.f};
        c4v = __builtin_amdgcn_mfma_f32_16x16x32_bf16(ab, bb, c4v, 0, 0, 0);
        float bv = bdt[e];
#pragma unroll
        for (int j = 0; j < 4; j++) {
            float xv = c4v[j] + bv;
            float sp = (xv > 20.f) ? xv : log1pf(__expf(xv));
            deltab[(size_t)(t0 + row4 + j) * E_ + e] = f2bf(sp);
        }
    }
}

// ---------------- chunked selective scan, s-in-registers (bf16 inputs, bf16 hend) ----------------
__global__ __launch_bounds__(256) void scan_p1(const short* __restrict__ deltab,
                                               const short* __restrict__ ucb,
                                               const float* __restrict__ xdbl,
                                               const float* __restrict__ A_log,
                                               short* __restrict__ hend,
                                               float* __restrict__ cumd) {
    int blk = blockIdx.x;            // b*(NC_*4) + c*4 + eq
    int eq = blk & 3;
    int c = (blk >> 2) & (NC_ - 1);
    int b = blk >> 8;
    int tid = threadIdx.x;
    int e = eq * 256 + tid;
    __shared__ float Bsl[CH_][16];
    int base = (b * N_ + c * CH_) * 64;
    for (int i = tid; i < CH_ * 16; i += 256) {
        int n = i >> 4, col = i & 15;
        Bsl[n][col] = xdbl[base + n * 64 + R_ + col];
    }
    float Aes[16];
    const float4* al = (const float4*)(A_log + e * 16);
#pragma unroll
    for (int j = 0; j < 4; j++) {
        float4 a = al[j];
        Aes[j * 4 + 0] = -__expf(a.x);
        Aes[j * 4 + 1] = -__expf(a.y);
        Aes[j * 4 + 2] = -__expf(a.z);
        Aes[j * 4 + 3] = -__expf(a.w);
    }
    __syncthreads();
    float h[16];
#pragma unroll
    for (int s = 0; s < 16; s++) h[s] = 0.f;
    float cum = 0.f;
    const short* dp = deltab + (size_t)(b * N_ + c * CH_) * E_ + e;
    const short* up = ucb + (size_t)(b * N_ + c * CH_) * E_ + e;
#pragma unroll 2
    for (int n = 0; n < CH_; n++) {
        float dv = bf2f(dp[n * E_]);
        float uv = bf2f(up[n * E_]);
        float du = dv * uv;
        cum += dv;
        float Bl[16];
#pragma unroll
        for (int j = 0; j < 4; j++) *(float4*)&Bl[j * 4] = *(const float4*)&Bsl[n][j * 4];
#pragma unroll
        for (int s = 0; s < 16; s++) {
            float dA = __expf(dv * Aes[s]);
            h[s] = fmaf(dA, h[s], du * Bl[s]);
        }
    }
    size_t ob = (size_t)(b * NC_ + c) * 16 * E_ + e;
#pragma unroll
    for (int s = 0; s < 16; s++) hend[ob + (size_t)s * E_] = f2bf(h[s]);
    cumd[(size_t)(b * NC_ + c) * E_ + e] = cum;
}

// ---- comb: wave-parallel Kogge-Stone over chunks; block = (b, s, 64-e tile) ----
__global__ __launch_bounds__(256) void scan_comb(short* __restrict__ hend,
                                                 const float* __restrict__ cumd,
                                                 const float* __restrict__ A_log) {
    __shared__ float lh[64][65];   // [c][e]
    __shared__ float lp[64][65];
    int blk = blockIdx.x;          // b*256 + s*16 + et
    int et = blk & 15;
    int s = (blk >> 4) & 15;
    int b = blk >> 8;
    int e0 = et * 64;
    int tid = threadIdx.x;
    int lane = tid & 63, w = tid >> 6;
    for (int i = tid; i < 64 * 64; i += 256) {
        int c = i >> 6, e = i & 63;
        lh[c][e] = bf2f(hend[((size_t)((b * NC_ + c) * 16) + s) * E_ + e0 + e]);
        lp[c][e] = cumd[(size_t)(b * NC_ + c) * E_ + e0 + e];
    }
    __syncthreads();
#pragma unroll 4
    for (int q = 0; q < 16; q++) {
        int e = w * 16 + q;
        float Aes = -__expf(A_log[(e0 + e) * 16 + s]);
        float A = __expf(Aes * lp[lane][e]);
        float Bv = lh[lane][e];
#pragma unroll
        for (int off = 1; off < 64; off <<= 1) {
            float Ap = __shfl_up(A, off);
            float Bp = __shfl_up(Bv, off);
            if (lane >= off) {
                Bv = fmaf(A, Bp, Bv);
                A *= Ap;
            }
        }
        float hB = __shfl_up(Bv, 1);
        lh[lane][e] = (lane == 0) ? 0.f : hB;   // exclusive scan result
    }
    __syncthreads();
    for (int i = tid; i < 64 * 64; i += 256) {
        int c = i >> 6, e = i & 63;
        hend[((size_t)((b * NC_ + c) * 16) + s) * E_ + e0 + e] = f2bf(lh[c][e]);
    }
}

__global__ __launch_bounds__(256) void scan_p3(const short* __restrict__ deltab,
                                               const short* __restrict__ ucb,
                                               const float* __restrict__ xdbl,
                                               const short* __restrict__ xzb,
                                               const float* __restrict__ A_log,
                                               const float* __restrict__ D_skip,
                                               const short* __restrict__ hend,
                                               short* __restrict__ yb) {
    int blk = blockIdx.x;
    int eq = blk & 3;
    int c = (blk >> 2) & (NC_ - 1);
    int b = blk >> 8;
    int tid = threadIdx.x;
    int e = eq * 256 + tid;
    __shared__ float Bsl[CH_][16];
    __shared__ float Csl[CH_][16];
    int base = (b * N_ + c * CH_) * 64;
    for (int i = tid; i < CH_ * 32; i += 256) {
        int n = i >> 5, col = i & 31;
        float v = xdbl[base + n * 64 + R_ + col];
        if (col < 16) Bsl[n][col] = v;
        else Csl[n][col - 16] = v;
    }
    float Aes[16];
    const float4* al = (const float4*)(A_log + e * 16);
#pragma unroll
    for (int j = 0; j < 4; j++) {
        float4 a = al[j];
        Aes[j * 4 + 0] = -__expf(a.x);
        Aes[j * 4 + 1] = -__expf(a.y);
        Aes[j * 4 + 2] = -__expf(a.z);
        Aes[j * 4 + 3] = -__expf(a.w);
    }
    float dsk = D_skip[e];
    float h[16];
    size_t ob = (size_t)(b * NC_ + c) * 16 * E_ + e;
#pragma unroll
    for (int s = 0; s < 16; s++) h[s] = bf2f(hend[ob + (size_t)s * E_]);
    __syncthreads();
    const short* dp = deltab + (size_t)(b * N_ + c * CH_) * E_ + e;
    const short* up = ucb + (size_t)(b * N_ + c * CH_) * E_ + e;
    const short* zp = xzb + (size_t)(b * N_ + c * CH_) * (2 * E_) + E_ + e;
    short* yp = yb + (size_t)(b * N_ + c * CH_) * E_ + e;
#pragma unroll 2
    for (int n = 0; n < CH_; n++) {
        float dv = bf2f(dp[n * E_]);
        float uv = bf2f(up[n * E_]);
        float du = dv * uv;
        float Bl[16], Cl[16];
#pragma unroll
        for (int j = 0; j < 4; j++) {
            *(float4*)&Bl[j * 4] = *(const float4*)&Bsl[n][j * 4];
            *(float4*)&Cl[j * 4] = *(const float4*)&Csl[n][j * 4];
        }
        float y = 0.f;
#pragma unroll
        for (int s = 0; s < 16; s++) {
            float dA = __expf(dv * Aes[s]);
            h[s] = fmaf(dA, h[s], du * Bl[s]);
            y = fmaf(h[s], Cl[s], y);
        }
        float zv = bf2f(zp[n * 2 * E_]);
        float yy = y + dsk * uv;
        yy = yy * (zv / (1.f + __expf(-zv)));
        yp[n * E_] = f2bf(yy);
    }
}

extern "C" void kernel_launch(void* const* d_in, const int* in_sizes, int n_in,
                              void* d_out, int out_size, void* d_ws, size_t ws_size,
                              hipStream_t stream) {
    const float* x       = (const float*)d_in[0];
    const float* cond    = (const float*)d_in[1];
    const float* ln_g    = (const float*)d_in[2];
    const float* ln_b    = (const float*)d_in[3];
    const float* W_in    = (const float*)d_in[4];
    const float* conv_w  = (const float*)d_in[5];
    const float* conv_b  = (const float*)d_in[6];
    const float* W_x     = (const float*)d_in[7];
    const float* W_dt    = (const float*)d_in[8];
    const float* b_dt    = (const float*)d_in[9];
    const float* A_log   = (const float*)d_in[10];
    const float* D_skip  = (const float*)d_in[11];
    const float* W_out   = (const float*)d_in[12];
    const float* film_gw = (const float*)d_in[13];
    const float* film_gb = (const float*)d_in[14];
    const float* film_bw = (const float*)d_in[15];
    const float* film_bb = (const float*)d_in[16];
    float* out = (float*)d_out;

    float* ws = (float*)d_ws;
    float* xdbl  = ws;                       //   262,144 f
    float* gamma = xdbl + 262144;            //     1,024 f
    float* beta  = gamma + 1024;             //     1,024 f
    float* cumd  = beta + 1024;              //   131,072 f  (B*NC*E)
    short* hend  = (short*)(cumd + 131072);  // 2,097,152 sh (bf16, B*NC*S*E)
    short* xzb   = hend + 2097152;           // 8,388,608 sh (bf16 xz)
    short* ucb   = xzb + 8388608;            // 4,194,304 sh (bf16 uc)
    short* deltab = ucb + 4194304;           // 4,194,304 sh (bf16 delta)
    short* Wint  = deltab + 4194304;         // 1,048,576 sh
    short* Woutt = Wint + 1048576;           //   524,288 sh
    short* yb    = Woutt + 524288;           // 4,194,304 sh
    short* Wxt   = yb + 4194304;             //    65,536 sh
    short* Wdtt  = Wxt + 65536;              //    32,768 sh
    short* xnb   = Wdtt + 32768;             // 2,097,152 sh (bf16 LN(x))

    // K1: LN stats+apply + W_in^T (2048 blocks)
    prep1_kernel<<<2048, 256, 0, stream>>>(x, xnb, ln_g, ln_b, W_in, Wint);

    // K2: gemm1 (512 XCD-swizzled tiles) + film + W_out^T + W_x^T + W_dt^T (1128 blocks)
    gemm1_hybrid<<<1128, 256, 0, stream>>>(
        xnb, Wint, xzb, W_out, Woutt, W_x, Wxt, W_dt, Wdtt,
        cond, film_gw, film_gb, film_bw, film_bb, gamma, beta);

    // conv+silu -> xproj -> dt, fused; 256 blocks x 8 waves, 16 tokens each
    mid_kernel<<<B_ * N_ / 16, 512, 0, stream>>>(
        xzb, conv_w, conv_b, Wxt, Wdtt, b_dt, ucb, xdbl, deltab);

    scan_p1<<<B_ * NC_ * 4, 256, 0, stream>>>(deltab, ucb, xdbl, A_log, hend, cumd);
    scan_comb<<<B_ * S_ * (E_ / 64), 256, 0, stream>>>(hend, cumd, A_log);
    scan_p3<<<B_ * NC_ * 4, 256, 0, stream>>>(deltab, ucb, xdbl, xzb, A_log, D_skip, hend, yb);

    // out = FiLM(y @ W_out)   [4096,1024]x[1024,512], 64x64 tiles, XCD-swizzled
    gemm2_kernel<64, 64>
        <<<512, 256, 0, stream>>>(
            yb, Woutt, out, B_ * N_, D_, E_, gamma, beta);
}

// Round 19
// 126.908 us; speedup vs baseline: 1.1294x; 1.0121x over previous
//
#include <hip/hip_runtime.h>
#include <hip/hip_bf16.h>
#include <math.h>

#define B_ 2
#define N_ 2048
#define D_ 512
#define E_ 1024
#define S_ 16
#define R_ 32
#define C_ 512
#define CH_ 32
#define NC_ 64     // chunks of 32 tokens

using short8 = __attribute__((ext_vector_type(8))) short;
using f32x4  = __attribute__((ext_vector_type(4))) float;
using f32x16 = __attribute__((ext_vector_type(16))) float;

__device__ __forceinline__ short f2bf(float f) {
    union { float f; unsigned u; } x; x.f = f;
    unsigned r = (x.u + 0x7fffu + ((x.u >> 16) & 1u)) >> 16;
    return (short)r;
}
__device__ __forceinline__ float bf2f(short s) {
    union { unsigned u; float f; } x;
    x.u = ((unsigned)(unsigned short)s) << 16;
    return x.f;
}
// fast sigmoid: v_rcp_f32 (1 ulp) instead of the ~10-op precise-division sequence
__device__ __forceinline__ float fsig(float a) {
    return __builtin_amdgcn_rcpf(1.f + __expf(-a));
}
// wave-level async global->LDS, 16B per lane (lds dest wave-uniform base + lane*16)
__device__ __forceinline__ void gl_lds16(const void* g, void* l) {
    __builtin_amdgcn_global_load_lds((const __attribute__((address_space(1))) void*)g,
                                     (__attribute__((address_space(3))) void*)l, 16, 0, 0);
}

__device__ __forceinline__ void transpose32(const float* __restrict__ W, short* __restrict__ Wt,
                                            int K, int N, int bx, int by, float (*t)[33], int tid) {
    int n0 = bx * 32, k0 = by * 32;
    int c = tid & 31, rr0 = tid >> 5;
#pragma unroll
    for (int rr = rr0; rr < 32; rr += 8)
        t[rr][c] = W[(size_t)(k0 + rr) * N + n0 + c];
    __syncthreads();
#pragma unroll
    for (int rr = rr0; rr < 32; rr += 8)
        Wt[(size_t)(n0 + rr) * K + k0 + c] = f2bf(t[c][rr]);
}

// ================= K1: LN stats+apply (wave/token) | W_in^T =================
__global__ __launch_bounds__(256) void prep1_kernel(
    const float* __restrict__ x, short* __restrict__ xnb,
    const float* __restrict__ lng, const float* __restrict__ lnb,
    const float* __restrict__ W_in, short* __restrict__ Wint) {
    __shared__ __align__(16) float smem[32 * 33];
    int bid = blockIdx.x;
    int tid = threadIdx.x;
    if (bid < 1024) {
        int t = bid * 4 + (tid >> 6);
        int lane = tid & 63;
        const float* src = x + (size_t)t * D_ + lane * 8;
        float4 v0 = *(const float4*)src;
        float4 v1 = *(const float4*)(src + 4);
        float s = v0.x + v0.y + v0.z + v0.w + v1.x + v1.y + v1.z + v1.w;
        float s2 = v0.x * v0.x;
        s2 = fmaf(v0.y, v0.y, s2); s2 = fmaf(v0.z, v0.z, s2); s2 = fmaf(v0.w, v0.w, s2);
        s2 = fmaf(v1.x, v1.x, s2); s2 = fmaf(v1.y, v1.y, s2);
        s2 = fmaf(v1.z, v1.z, s2); s2 = fmaf(v1.w, v1.w, s2);
#pragma unroll
        for (int o = 32; o >= 1; o >>= 1) {
            s += __shfl_xor(s, o);
            s2 += __shfl_xor(s2, o);
        }
        float mu = s * (1.f / (float)D_);
        float var = s2 * (1.f / (float)D_) - mu * mu;
        float rs = rsqrtf(var + 1e-5f);
        float4 g0 = *(const float4*)(lng + lane * 8);
        float4 g1 = *(const float4*)(lng + lane * 8 + 4);
        float4 b0 = *(const float4*)(lnb + lane * 8);
        float4 b1 = *(const float4*)(lnb + lane * 8 + 4);
        short8 o;
        o[0] = f2bf((v0.x - mu) * rs * g0.x + b0.x);
        o[1] = f2bf((v0.y - mu) * rs * g0.y + b0.y);
        o[2] = f2bf((v0.z - mu) * rs * g0.z + b0.z);
        o[3] = f2bf((v0.w - mu) * rs * g0.w + b0.w);
        o[4] = f2bf((v1.x - mu) * rs * g1.x + b1.x);
        o[5] = f2bf((v1.y - mu) * rs * g1.y + b1.y);
        o[6] = f2bf((v1.z - mu) * rs * g1.z + b1.z);
        o[7] = f2bf((v1.w - mu) * rs * g1.w + b1.w);
        *(short8*)(xnb + (size_t)t * D_ + lane * 8) = o;
    } else {
        int r = bid - 1024;
        transpose32(W_in, Wint, 512, 2048, r % 64, r / 64, (float(*)[33])smem, tid);
    }
}

// ================= K2 hybrid: gemm1 tiles | film | W_out^T | W_x^T | W_dt^T =================
__global__ __launch_bounds__(256) void gemm1_hybrid(
    const short* __restrict__ A, const short* __restrict__ Bt, short* __restrict__ Cb,
    const float* __restrict__ W_out, short* __restrict__ Woutt,
    const float* __restrict__ W_x, short* __restrict__ Wxt,
    const float* __restrict__ W_dt, short* __restrict__ Wdtt,
    const float* __restrict__ cond,
    const float* __restrict__ gw, const float* __restrict__ gb,
    const float* __restrict__ bw, const float* __restrict__ bb,
    float* __restrict__ gamma, float* __restrict__ beta) {
    __shared__ __align__(16) char smem[32768];
    int bid = blockIdx.x;
    int tid = threadIdx.x;
    if (bid < 512) {
        constexpr int BM = 128, BN = 128, BK = 64;
        constexpr int N = 2048, K = 512;
        short* As = (short*)smem;
        short* Bs = As + BM * BK;
        int lane = tid & 63, w = tid >> 6;
        int wr = w >> 1, wc = w & 1;
        int swz = (bid & 7) * 64 + (bid >> 3);
        int m0 = (swz >> 4) * BM, n0 = (swz & 15) * BN;
        int lr = lane >> 3, lc = lane & 7;
        f32x16 acc[2][2];
#pragma unroll
        for (int i = 0; i < 2; i++)
#pragma unroll
            for (int j = 0; j < 2; j++)
#pragma unroll
                for (int r = 0; r < 16; r++) acc[i][j][r] = 0.f;
        int l31 = lane & 31, hk = (lane >> 5) * 8;
        for (int k0 = 0; k0 < K; k0 += BK) {
            __syncthreads();
#pragma unroll
            for (int ch = w; ch < BM / 8; ch += 4)
                gl_lds16(&A[(size_t)(m0 + ch * 8 + lr) * K + k0 + lc * 8], &As[ch * 512]);
#pragma unroll
            for (int ch = w; ch < BN / 8; ch += 4)
                gl_lds16(&Bt[(size_t)(n0 + ch * 8 + lr) * K + k0 + lc * 8], &Bs[ch * 512]);
            __syncthreads();
#pragma unroll
            for (int kk = 0; kk < 4; kk++) {
                short8 a[2], b[2];
#pragma unroll
                for (int i = 0; i < 2; i++)
                    a[i] = *(const short8*)&As[(wr * 64 + i * 32 + l31) * BK + kk * 16 + hk];
#pragma unroll
                for (int j = 0; j < 2; j++)
                    b[j] = *(const short8*)&Bs[(wc * 64 + j * 32 + l31) * BK + kk * 16 + hk];
#pragma unroll
                for (int i = 0; i < 2; i++)
#pragma unroll
                    for (int j = 0; j < 2; j++)
                        acc[i][j] = __builtin_amdgcn_mfma_f32_32x32x16_bf16(a[i], b[j], acc[i][j], 0, 0, 0);
            }
        }
        int rbase = 4 * (lane >> 5);
#pragma unroll
        for (int i = 0; i < 2; i++)
#pragma unroll
            for (int j = 0; j < 2; j++) {
                int col = n0 + wc * 64 + j * 32 + l31;
#pragma unroll
                for (int r = 0; r < 16; r++) {
                    int row = m0 + wr * 64 + i * 32 + rbase + (r & 3) + 8 * (r >> 2);
                    Cb[(size_t)row * N + col] = f2bf(acc[i][j][r]);
                }
            }
    } else if (bid < 520) {
        float* cs = (float*)smem;           // [2][512]
        float* red = (float*)smem + 1024;   // [4][64][4]
        int d0 = (bid - 512) * 64;
#pragma unroll
        for (int i = tid; i < 2 * C_ / 4; i += 256) {
            int b = i >> 7;
            int c4 = (i & 127) * 4;
            *(float4*)&cs[b * C_ + c4] = *(const float4*)(cond + (size_t)b * C_ + c4);
        }
        __syncthreads();
        int dl = tid & 63, ks = tid >> 6;
        int d = d0 + dl;
        float g0 = 0.f, g1 = 0.f, bt0 = 0.f, bt1 = 0.f;
#pragma unroll 4
        for (int k = ks * 128; k < ks * 128 + 128; k++) {
            float wg = gw[(size_t)k * D_ + d];
            float wb = bw[(size_t)k * D_ + d];
            float c0 = cs[k], c1 = cs[C_ + k];
            g0 = fmaf(c0, wg, g0);
            g1 = fmaf(c1, wg, g1);
            bt0 = fmaf(c0, wb, bt0);
            bt1 = fmaf(c1, wb, bt1);
        }
        red[(ks * 64 + dl) * 4 + 0] = g0; red[(ks * 64 + dl) * 4 + 1] = g1;
        red[(ks * 64 + dl) * 4 + 2] = bt0; red[(ks * 64 + dl) * 4 + 3] = bt1;
        __syncthreads();
        if (ks == 0) {
            float s0 = 0.f, s1 = 0.f, s2 = 0.f, s3 = 0.f;
#pragma unroll
            for (int q = 0; q < 4; q++) {
                s0 += red[(q * 64 + dl) * 4 + 0]; s1 += red[(q * 64 + dl) * 4 + 1];
                s2 += red[(q * 64 + dl) * 4 + 2]; s3 += red[(q * 64 + dl) * 4 + 3];
            }
            float gbv = gb[d], bbv = bb[d];
            gamma[d] = s0 + gbv;
            gamma[D_ + d] = s1 + gbv;
            beta[d] = s2 + bbv;
            beta[D_ + d] = s3 + bbv;
        }
    } else if (bid < 1032) {
        int r = bid - 520;
        transpose32(W_out, Woutt, 1024, 512, r % 16, r / 16, (float(*)[33])smem, tid);
    } else if (bid < 1096) {
        int r = bid - 1032;
        transpose32(W_x, Wxt, 1024, 64, r % 2, r / 2, (float(*)[33])smem, tid);
    } else {
        int r = bid - 1096;
        transpose32(W_dt, Wdtt, 32, 1024, r, 0, (float(*)[33])smem, tid);
    }
}

// ---------------- gemm2: C[M][N] = A[M][K] * Bt[N][K]^T, FiLM, fp32 out ----------------
template <int BM, int BN>
__global__ __launch_bounds__(256) void gemm2_kernel(
    const short* __restrict__ A, const short* __restrict__ Bt, float* __restrict__ Cf,
    int M, int N, int K,
    const float* __restrict__ gamma, const float* __restrict__ beta) {
    constexpr int BK = 64;
    constexpr int WM = BM / 2, WN = BN / 2;
    constexpr int MR = WM / 32, NR = WN / 32;
    __shared__ __align__(16) short As[BM * BK];
    __shared__ __align__(16) short Bs[BN * BK];
    int tid = threadIdx.x;
    int lane = tid & 63, w = tid >> 6;
    int wr = w >> 1, wc = w & 1;
    int lid = blockIdx.x;
    int chunk = gridDim.x >> 3;
    int swz = (lid & 7) * chunk + (lid >> 3);
    int ntiles = N / BN;
    int m0 = (swz / ntiles) * BM, n0 = (swz % ntiles) * BN;
    int lr = lane >> 3, lc = lane & 7;

    f32x16 acc[MR][NR];
#pragma unroll
    for (int i = 0; i < MR; i++)
#pragma unroll
        for (int j = 0; j < NR; j++)
#pragma unroll
            for (int r = 0; r < 16; r++) acc[i][j][r] = 0.f;

    int l31 = lane & 31, hk = (lane >> 5) * 8;

    for (int k0 = 0; k0 < K; k0 += BK) {
        __syncthreads();
#pragma unroll
        for (int ch = w; ch < BM / 8; ch += 4)
            gl_lds16(&A[(size_t)(m0 + ch * 8 + lr) * K + k0 + lc * 8], &As[ch * 512]);
#pragma unroll
        for (int ch = w; ch < BN / 8; ch += 4)
            gl_lds16(&Bt[(size_t)(n0 + ch * 8 + lr) * K + k0 + lc * 8], &Bs[ch * 512]);
        __syncthreads();
#pragma unroll
        for (int kk = 0; kk < 4; kk++) {
            short8 a[MR], b[NR];
#pragma unroll
            for (int i = 0; i < MR; i++)
                a[i] = *(const short8*)&As[(wr * WM + i * 32 + l31) * BK + kk * 16 + hk];
#pragma unroll
            for (int j = 0; j < NR; j++)
                b[j] = *(const short8*)&Bs[(wc * WN + j * 32 + l31) * BK + kk * 16 + hk];
#pragma unroll
            for (int i = 0; i < MR; i++)
#pragma unroll
                for (int j = 0; j < NR; j++)
                    acc[i][j] = __builtin_amdgcn_mfma_f32_32x32x16_bf16(a[i], b[j], acc[i][j], 0, 0, 0);
        }
    }
    int rbase = 4 * (lane >> 5);
    int bi = m0 >> 11;
#pragma unroll
    for (int i = 0; i < MR; i++)
#pragma unroll
        for (int j = 0; j < NR; j++) {
            int col = n0 + wc * WN + j * 32 + l31;
            float gm = gamma[bi * D_ + col];
            float bt = beta[bi * D_ + col];
#pragma unroll
            for (int r = 0; r < 16; r++) {
                int row = m0 + wr * WM + i * 32 + rbase + (r & 3) + 8 * (r >> 2);
                Cf[(size_t)row * N + col] = gm * acc[i][j][r] + bt;
            }
        }
}

// ================= mid: sliding-window conv -> xproj -> dt; 16 tok/block, 8 waves =================
__global__ __launch_bounds__(512) void mid_kernel(
    const short* __restrict__ xzb, const float* __restrict__ cw, const float* __restrict__ cb,
    const short* __restrict__ Wxt,   // [64][1024] bf16
    const short* __restrict__ Wdtt,  // [1024][32] bf16
    const float* __restrict__ bdt,
    short* __restrict__ ucb, float* __restrict__ xdbl, short* __restrict__ deltab) {
    constexpr int LDU = 1032;                        // 2064B pitch
    __shared__ __align__(16) short u[16 * LDU];      // 33 KB uc (bf16)
    __shared__ __align__(16) float xd2[2][16 * 68];  // 8.7 KB x_dbl partials
    int tid = threadIdx.x;
    int t0 = blockIdx.x * 16;
    int n0 = t0 & (N_ - 1);
    // ---- conv+SiLU: thread -> 8-wide e-chunk, 4 tokens; 7-row sliding window ----
    {
        int c8 = (tid & 127) * 8;
        int base = (tid >> 7) * 4;
        float4 wv[8];
        float cbv[8];
#pragma unroll
        for (int j = 0; j < 8; j++) {
            wv[j] = *(const float4*)(cw + (c8 + j) * 4);
            cbv[j] = cb[c8 + j];
        }
        float uf[7][8];
#pragma unroll
        for (int j = 0; j < 7; j++) {
            short8 v = {0, 0, 0, 0, 0, 0, 0, 0};
            if (n0 + base - 3 + j >= 0)
                v = *(const short8*)&xzb[(size_t)(t0 + base - 3 + j) * (2 * E_) + c8];
#pragma unroll
            for (int q = 0; q < 8; q++) uf[j][q] = bf2f(v[q]);
        }
#pragma unroll
        for (int k = 0; k < 4; k++) {
            int n = base + k;
            short8 o;
#pragma unroll
            for (int q = 0; q < 8; q++) {
                float a = fmaf(wv[q].x, uf[k][q],
                          fmaf(wv[q].y, uf[k + 1][q],
                          fmaf(wv[q].z, uf[k + 2][q],
                          fmaf(wv[q].w, uf[k + 3][q], cbv[q]))));
                float v = a * fsig(a);
                o[q] = f2bf(v);
            }
            *(short8*)&ucb[(size_t)(t0 + n) * E_ + c8] = o;
            *(short8*)&u[n * LDU + c8] = o;
        }
    }
    __syncthreads();
    // ---- xproj: 8 waves; wave w -> cols [cg*16,+16), K-half kh ----
    int lane = tid & 63, w = tid >> 6;
    int cg = w & 3, kh = w >> 2;
    int l15 = lane & 15, kq = (lane >> 4) * 8;
    f32x4 acc4 = {0.f, 0.f, 0.f, 0.f};
#pragma unroll 8
    for (int k0 = 0; k0 < 16; k0++) {
        int kk = kh * 512 + k0 * 32;
        short8 af = *(const short8*)&u[l15 * LDU + kk + kq];
        short8 bfr = *(const short8*)&Wxt[(size_t)(cg * 16 + l15) * E_ + kk + kq];
        acc4 = __builtin_amdgcn_mfma_f32_16x16x32_bf16(af, bfr, acc4, 0, 0, 0);
    }
#pragma unroll
    for (int j = 0; j < 4; j++)
        xd2[kh][((lane >> 4) * 4 + j) * 68 + cg * 16 + l15] = acc4[j];
    __syncthreads();
    if (tid < 256) {
        int r = tid >> 4, c4 = (tid & 15) * 4;
        float4 a = *(const float4*)&xd2[0][r * 68 + c4];
        float4 b = *(const float4*)&xd2[1][r * 68 + c4];
        a.x += b.x; a.y += b.y; a.z += b.z; a.w += b.w;
        *(float4*)&xd2[0][r * 68 + c4] = a;
        *(float4*)&xdbl[(size_t)(t0 + r) * 64 + c4] = a;
    }
    __syncthreads();
    // ---- dt: 8 waves x 8 e-tiles of 16 ----
    float av[8];
    *(float4*)&av[0] = *(const float4*)&xd2[0][l15 * 68 + kq];
    *(float4*)&av[4] = *(const float4*)&xd2[0][l15 * 68 + kq + 4];
    short8 ab;
#pragma unroll
    for (int j = 0; j < 8; j++) ab[j] = f2bf(av[j]);
    int row4 = (lane >> 4) * 4;
#pragma unroll 4
    for (int t = 0; t < 8; t++) {
        int e = w * 128 + t * 16 + l15;
        short8 bb = *(const short8*)&Wdtt[(size_t)e * 32 + kq];
        f32x4 c4v = {0.f, 0.f, 0.f, 0.f};
        c4v = __builtin_amdgcn_mfma_f32_16x16x32_bf16(ab, bb, c4v, 0, 0, 0);
        float bv = bdt[e];
#pragma unroll
        for (int j = 0; j < 4; j++) {
            float xv = c4v[j] + bv;
            float sp = (xv > 20.f) ? xv : log1pf(__expf(xv));
            deltab[(size_t)(t0 + row4 + j) * E_ + e] = f2bf(sp);
        }
    }
}

// ---------------- chunked selective scan, s-in-registers (bf16 inputs, bf16 hend) ----------------
__global__ __launch_bounds__(256) void scan_p1(const short* __restrict__ deltab,
                                               const short* __restrict__ ucb,
                                               const float* __restrict__ xdbl,
                                               const float* __restrict__ A_log,
                                               short* __restrict__ hend,
                                               float* __restrict__ cumd) {
    int blk = blockIdx.x;            // b*(NC_*4) + c*4 + eq
    int eq = blk & 3;
    int c = (blk >> 2) & (NC_ - 1);
    int b = blk >> 8;
    int tid = threadIdx.x;
    int e = eq * 256 + tid;
    __shared__ float Bsl[CH_][16];
    int base = (b * N_ + c * CH_) * 64;
    for (int i = tid; i < CH_ * 16; i += 256) {
        int n = i >> 4, col = i & 15;
        Bsl[n][col] = xdbl[base + n * 64 + R_ + col];
    }
    float Aes[16];
    const float4* al = (const float4*)(A_log + e * 16);
#pragma unroll
    for (int j = 0; j < 4; j++) {
        float4 a = al[j];
        Aes[j * 4 + 0] = -__expf(a.x);
        Aes[j * 4 + 1] = -__expf(a.y);
        Aes[j * 4 + 2] = -__expf(a.z);
        Aes[j * 4 + 3] = -__expf(a.w);
    }
    __syncthreads();
    float h[16];
#pragma unroll
    for (int s = 0; s < 16; s++) h[s] = 0.f;
    float cum = 0.f;
    const short* dp = deltab + (size_t)(b * N_ + c * CH_) * E_ + e;
    const short* up = ucb + (size_t)(b * N_ + c * CH_) * E_ + e;
#pragma unroll 2
    for (int n = 0; n < CH_; n++) {
        float dv = bf2f(dp[n * E_]);
        float uv = bf2f(up[n * E_]);
        float du = dv * uv;
        cum += dv;
        float Bl[16];
#pragma unroll
        for (int j = 0; j < 4; j++) *(float4*)&Bl[j * 4] = *(const float4*)&Bsl[n][j * 4];
#pragma unroll
        for (int s = 0; s < 16; s++) {
            float dA = __expf(dv * Aes[s]);
            h[s] = fmaf(dA, h[s], du * Bl[s]);
        }
    }
    size_t ob = (size_t)(b * NC_ + c) * 16 * E_ + e;
#pragma unroll
    for (int s = 0; s < 16; s++) hend[ob + (size_t)s * E_] = f2bf(h[s]);
    cumd[(size_t)(b * NC_ + c) * E_ + e] = cum;
}

// ---- comb: wave-parallel Kogge-Stone over chunks; block = (b, s, 64-e tile) ----
__global__ __launch_bounds__(256) void scan_comb(short* __restrict__ hend,
                                                 const float* __restrict__ cumd,
                                                 const float* __restrict__ A_log) {
    __shared__ float lh[64][65];   // [c][e]
    __shared__ float lp[64][65];
    int blk = blockIdx.x;          // b*256 + s*16 + et
    int et = blk & 15;
    int s = (blk >> 4) & 15;
    int b = blk >> 8;
    int e0 = et * 64;
    int tid = threadIdx.x;
    int lane = tid & 63, w = tid >> 6;
    for (int i = tid; i < 64 * 64; i += 256) {
        int c = i >> 6, e = i & 63;
        lh[c][e] = bf2f(hend[((size_t)((b * NC_ + c) * 16) + s) * E_ + e0 + e]);
        lp[c][e] = cumd[(size_t)(b * NC_ + c) * E_ + e0 + e];
    }
    __syncthreads();
#pragma unroll 4
    for (int q = 0; q < 16; q++) {
        int e = w * 16 + q;
        float Aes = -__expf(A_log[(e0 + e) * 16 + s]);
        float A = __expf(Aes * lp[lane][e]);
        float Bv = lh[lane][e];
#pragma unroll
        for (int off = 1; off < 64; off <<= 1) {
            float Ap = __shfl_up(A, off);
            float Bp = __shfl_up(Bv, off);
            if (lane >= off) {
                Bv = fmaf(A, Bp, Bv);
                A *= Ap;
            }
        }
        float hB = __shfl_up(Bv, 1);
        lh[lane][e] = (lane == 0) ? 0.f : hB;   // exclusive scan result
    }
    __syncthreads();
    for (int i = tid; i < 64 * 64; i += 256) {
        int c = i >> 6, e = i & 63;
        hend[((size_t)((b * NC_ + c) * 16) + s) * E_ + e0 + e] = f2bf(lh[c][e]);
    }
}

__global__ __launch_bounds__(256) void scan_p3(const short* __restrict__ deltab,
                                               const short* __restrict__ ucb,
                                               const float* __restrict__ xdbl,
                                               const short* __restrict__ xzb,
                                               const float* __restrict__ A_log,
                                               const float* __restrict__ D_skip,
                                               const short* __restrict__ hend,
                                               short* __restrict__ yb) {
    int blk = blockIdx.x;
    int eq = blk & 3;
    int c = (blk >> 2) & (NC_ - 1);
    int b = blk >> 8;
    int tid = threadIdx.x;
    int e = eq * 256 + tid;
    __shared__ float Bsl[CH_][16];
    __shared__ float Csl[CH_][16];
    int base = (b * N_ + c * CH_) * 64;
    for (int i = tid; i < CH_ * 32; i += 256) {
        int n = i >> 5, col = i & 31;
        float v = xdbl[base + n * 64 + R_ + col];
        if (col < 16) Bsl[n][col] = v;
        else Csl[n][col - 16] = v;
    }
    float Aes[16];
    const float4* al = (const float4*)(A_log + e * 16);
#pragma unroll
    for (int j = 0; j < 4; j++) {
        float4 a = al[j];
        Aes[j * 4 + 0] = -__expf(a.x);
        Aes[j * 4 + 1] = -__expf(a.y);
        Aes[j * 4 + 2] = -__expf(a.z);
        Aes[j * 4 + 3] = -__expf(a.w);
    }
    float dsk = D_skip[e];
    float h[16];
    size_t ob = (size_t)(b * NC_ + c) * 16 * E_ + e;
#pragma unroll
    for (int s = 0; s < 16; s++) h[s] = bf2f(hend[ob + (size_t)s * E_]);
    __syncthreads();
    const short* dp = deltab + (size_t)(b * N_ + c * CH_) * E_ + e;
    const short* up = ucb + (size_t)(b * N_ + c * CH_) * E_ + e;
    const short* zp = xzb + (size_t)(b * N_ + c * CH_) * (2 * E_) + E_ + e;
    short* yp = yb + (size_t)(b * N_ + c * CH_) * E_ + e;
#pragma unroll 2
    for (int n = 0; n < CH_; n++) {
        float dv = bf2f(dp[n * E_]);
        float uv = bf2f(up[n * E_]);
        float du = dv * uv;
        float Bl[16], Cl[16];
#pragma unroll
        for (int j = 0; j < 4; j++) {
            *(float4*)&Bl[j * 4] = *(const float4*)&Bsl[n][j * 4];
            *(float4*)&Cl[j * 4] = *(const float4*)&Csl[n][j * 4];
        }
        float y = 0.f;
#pragma unroll
        for (int s = 0; s < 16; s++) {
            float dA = __expf(dv * Aes[s]);
            h[s] = fmaf(dA, h[s], du * Bl[s]);
            y = fmaf(h[s], Cl[s], y);
        }
        float zv = bf2f(zp[n * 2 * E_]);
        float yy = y + dsk * uv;
        yy = yy * (zv * fsig(zv));
        yp[n * E_] = f2bf(yy);
    }
}

extern "C" void kernel_launch(void* const* d_in, const int* in_sizes, int n_in,
                              void* d_out, int out_size, void* d_ws, size_t ws_size,
                              hipStream_t stream) {
    const float* x       = (const float*)d_in[0];
    const float* cond    = (const float*)d_in[1];
    const float* ln_g    = (const float*)d_in[2];
    const float* ln_b    = (const float*)d_in[3];
    const float* W_in    = (const float*)d_in[4];
    const float* conv_w  = (const float*)d_in[5];
    const float* conv_b  = (const float*)d_in[6];
    const float* W_x     = (const float*)d_in[7];
    const float* W_dt    = (const float*)d_in[8];
    const float* b_dt    = (const float*)d_in[9];
    const float* A_log   = (const float*)d_in[10];
    const float* D_skip  = (const float*)d_in[11];
    const float* W_out   = (const float*)d_in[12];
    const float* film_gw = (const float*)d_in[13];
    const float* film_gb = (const float*)d_in[14];
    const float* film_bw = (const float*)d_in[15];
    const float* film_bb = (const float*)d_in[16];
    float* out = (float*)d_out;

    float* ws = (float*)d_ws;
    float* xdbl  = ws;                       //   262,144 f
    float* gamma = xdbl + 262144;            //     1,024 f
    float* beta  = gamma + 1024;             //     1,024 f
    float* cumd  = beta + 1024;              //   131,072 f  (B*NC*E)
    short* hend  = (short*)(cumd + 131072);  // 2,097,152 sh (bf16, B*NC*S*E)
    short* xzb   = hend + 2097152;           // 8,388,608 sh (bf16 xz)
    short* ucb   = xzb + 8388608;            // 4,194,304 sh (bf16 uc)
    short* deltab = ucb + 4194304;           // 4,194,304 sh (bf16 delta)
    short* Wint  = deltab + 4194304;         // 1,048,576 sh
    short* Woutt = Wint + 1048576;           //   524,288 sh
    short* yb    = Woutt + 524288;           // 4,194,304 sh
    short* Wxt   = yb + 4194304;             //    65,536 sh
    short* Wdtt  = Wxt + 65536;              //    32,768 sh
    short* xnb   = Wdtt + 32768;             // 2,097,152 sh (bf16 LN(x))

    // K1: LN stats+apply + W_in^T (2048 blocks)
    prep1_kernel<<<2048, 256, 0, stream>>>(x, xnb, ln_g, ln_b, W_in, Wint);

    // K2: gemm1 (512 XCD-swizzled tiles) + film + W_out^T + W_x^T + W_dt^T (1128 blocks)
    gemm1_hybrid<<<1128, 256, 0, stream>>>(
        xnb, Wint, xzb, W_out, Woutt, W_x, Wxt, W_dt, Wdtt,
        cond, film_gw, film_gb, film_bw, film_bb, gamma, beta);

    // conv+silu -> xproj -> dt, fused; 256 blocks x 8 waves, 16 tokens each
    mid_kernel<<<B_ * N_ / 16, 512, 0, stream>>>(
        xzb, conv_w, conv_b, Wxt, Wdtt, b_dt, ucb, xdbl, deltab);

    scan_p1<<<B_ * NC_ * 4, 256, 0, stream>>>(deltab, ucb, xdbl, A_log, hend, cumd);
    scan_comb<<<B_ * S_ * (E_ / 64), 256, 0, stream>>>(hend, cumd, A_log);
    scan_p3<<<B_ * NC_ * 4, 256, 0, stream>>>(deltab, ucb, xdbl, xzb, A_log, D_skip, hend, yb);

    // out = FiLM(y @ W_out)   [4096,1024]x[1024,512], 64x64 tiles, XCD-swizzled
    gemm2_kernel<64, 64>
        <<<512, 256, 0, stream>>>(
            yb, Woutt, out, B_ * N_, D_, E_, gamma, beta);
}